// Round 1
// baseline (28630.215 us; speedup 1.0000x reference)
//
#include <hip/hip_runtime.h>
#include <math.h>

#define B_ 64
#define S_ 512
#define I_ 256
#define H_ 1024
#define O_ 256

#define OUT_OFF (B_*O_)      // 16384 floats: final output
#define SLOT    (B_*H_)      // 65536 floats per hidden timestep slot

// ---------------- zero hidden slot 0 (h0 = 0) ----------------
__global__ void k_zero(float* __restrict__ hid) {
    int i = blockIdx.x * 256 + threadIdx.x;          // 64 blocks * 256 = 16384 float4
    ((float4*)hid)[i] = make_float4(0.f, 0.f, 0.f, 0.f);
}

// ---------------- generic transpose src[R][C] -> dst[C][R] ----------------
__global__ void k_transpose(const float* __restrict__ src, float* __restrict__ dst,
                            int R, int C) {
    __shared__ float tile[32][33];
    int c0 = blockIdx.x * 32, r0 = blockIdx.y * 32;
    int tx = threadIdx.x, ty = threadIdx.y;          // block (32,8)
#pragma unroll
    for (int j = 0; j < 32; j += 8)
        tile[ty + j][tx] = src[(size_t)(r0 + ty + j) * C + c0 + tx];
    __syncthreads();
#pragma unroll
    for (int j = 0; j < 32; j += 8)
        dst[(size_t)(c0 + ty + j) * R + r0 + tx] = tile[tx][ty + j];
}

// ---------------- x_proj: hid[t+1][b][h] = sum_i x[b][t][i] * W_ih[h][i] ----------------
// grid (S_, H_/64), 256 threads. Tile: all 64 b x 64 h, K=256 staged in LDS.
__global__ __launch_bounds__(256) void k_xproj(const float* __restrict__ x,
                                               const float* __restrict__ wihT, // [I_][H_]
                                               float* __restrict__ hid) {
    const int t   = blockIdx.x;
    const int hq0 = blockIdx.y * 16;                 // h-quad base (64 h per tile)
    __shared__ float xs[B_][260];                    // +4 pad: conflict-free broadcast reads
    const int tid = threadIdx.x;

    // stage x[b][t][0..255] for all 64 batches (coalesced float4)
#pragma unroll
    for (int it = 0; it < 16; ++it) {
        int f4 = it * 256 + tid;
        int b = f4 >> 6, iq = f4 & 63;
        float4 v = ((const float4*)x)[(size_t)b * (S_ * I_ / 4) + t * (I_ / 4) + iq];
        *(float4*)&xs[b][iq * 4] = v;
    }
    __syncthreads();

    const int hq = tid & 15;                         // h-quad within tile
    const int b0 = (tid >> 4) * 4;                   // 4 batches per thread
    float4 acc[4];
#pragma unroll
    for (int i = 0; i < 4; ++i) acc[i] = make_float4(0.f, 0.f, 0.f, 0.f);

    const float4* w4p = (const float4*)wihT;
#pragma unroll 4
    for (int k = 0; k < I_; ++k) {
        float4 w = w4p[(size_t)k * (H_ / 4) + hq0 + hq];
#pragma unroll
        for (int i = 0; i < 4; ++i) {
            float xv = xs[b0 + i][k];
            acc[i].x += xv * w.x; acc[i].y += xv * w.y;
            acc[i].z += xv * w.z; acc[i].w += xv * w.w;
        }
    }

    float4* out4 = (float4*)hid;
#pragma unroll
    for (int i = 0; i < 4; ++i)
        out4[(size_t)(t + 1) * (SLOT / 4) + (b0 + i) * (H_ / 4) + hq0 + hq] = acc[i];
}

// ---------------- one recurrence step ----------------
// hid[t+1][b][r] = tanh( hid[t+1][b][r](=x_proj) + bias[r] + sum_k WT[k][r]*hid[t][b][k] )
// grid (16,4): bx = 4-batch tile, by = 256-row tile. 256 threads: (rq = tid&63)*4 rows, b = tid>>6.
__global__ __launch_bounds__(256) void k_step(const float* __restrict__ WT,   // [H_][H_] = W_hh^T
                                              const float* __restrict__ bias,
                                              float* __restrict__ hid, int t) {
    const int bx = blockIdx.x;
    const int by = blockIdx.y;
    __shared__ float hs[4 * H_];
    const int tid = threadIdx.x;

    // stage h_t for this WG's 4 batches: 4096 contiguous floats
    const float4* hsrc = (const float4*)(hid + (size_t)t * SLOT + bx * 4 * H_);
#pragma unroll
    for (int it = 0; it < 4; ++it) {
        int f4 = it * 256 + tid;
        *(float4*)&hs[f4 * 4] = hsrc[f4];
    }
    __syncthreads();

    const int rq    = tid & 63;
    const int b     = tid >> 6;                      // wave-uniform -> broadcast LDS reads
    const int bglob = bx * 4 + b;
    const int rquad = by * 64 + rq;                  // quad index into H_/4

    float4* slot1 = (float4*)(hid + (size_t)(t + 1) * SLOT);
    float4 acc = slot1[bglob * (H_ / 4) + rquad];    // x_proj (in-place)
    float4 bs = ((const float4*)bias)[rquad];
    acc.x += bs.x; acc.y += bs.y; acc.z += bs.z; acc.w += bs.w;

    const float4* WT4 = (const float4*)WT;
    const float* hb = &hs[b * H_];
#pragma unroll 4
    for (int k = 0; k < H_; ++k) {
        float4 w = WT4[(size_t)k * (H_ / 4) + rquad];
        float hk = hb[k];
        acc.x += w.x * hk; acc.y += w.y * hk;
        acc.z += w.z * hk; acc.w += w.w * hk;
    }

    acc.x = tanhf(acc.x); acc.y = tanhf(acc.y);
    acc.z = tanhf(acc.z); acc.w = tanhf(acc.w);
    slot1[bglob * (H_ / 4) + rquad] = acc;
}

// ---------------- final fc: out[b][o] = h_S[b] . fc_w[o] + fc_b[o] ----------------
__global__ __launch_bounds__(256) void k_fc(const float* __restrict__ fcwT,  // [H_][O_]
                                            const float* __restrict__ fcb,
                                            const float* __restrict__ hid,
                                            float* __restrict__ outp) {
    const int b = blockIdx.x;
    __shared__ float hl[H_];
    const int tid = threadIdx.x;
    ((float4*)hl)[tid] = ((const float4*)(hid + (size_t)S_ * SLOT + b * H_))[tid];
    __syncthreads();
    float acc = fcb[tid];
#pragma unroll 4
    for (int k = 0; k < H_; ++k)
        acc += fcwT[(size_t)k * O_ + tid] * hl[k];
    outp[b * O_ + tid] = acc;
}

extern "C" void kernel_launch(void* const* d_in, const int* in_sizes, int n_in,
                              void* d_out, int out_size, void* d_ws, size_t ws_size,
                              hipStream_t stream) {
    const float* x    = (const float*)d_in[0];
    const float* wih  = (const float*)d_in[1];
    const float* whh  = (const float*)d_in[2];
    const float* bias = (const float*)d_in[3];
    const float* fcw  = (const float*)d_in[4];
    const float* fcb  = (const float*)d_in[5];

    float* outp = (float*)d_out;
    float* hid  = outp + OUT_OFF;

    // workspace layout (needs 6 MB): WT [1024][1024], wihT [256][1024], fcwT [1024][256]
    float* WT   = (float*)d_ws;
    float* wihT = WT + (size_t)H_ * H_;
    float* fcwT = wihT + (size_t)I_ * H_;

    k_zero<<<SLOT / 4 / 256, 256, 0, stream>>>(hid);
    k_transpose<<<dim3(H_ / 32, H_ / 32), dim3(32, 8), 0, stream>>>(whh, WT, H_, H_);
    k_transpose<<<dim3(I_ / 32, H_ / 32), dim3(32, 8), 0, stream>>>(wih, wihT, H_, I_);
    k_transpose<<<dim3(H_ / 32, O_ / 32), dim3(32, 8), 0, stream>>>(fcw, fcwT, O_, H_);

    k_xproj<<<dim3(S_, H_ / 64), 256, 0, stream>>>(x, wihT, hid);

    for (int t = 0; t < S_; ++t)
        k_step<<<dim3(16, 4), 256, 0, stream>>>(WT, bias, hid, t);

    k_fc<<<B_, 256, 0, stream>>>(fcwT, fcb, hid, outp);
}

// Round 2
// 3998.694 us; speedup vs baseline: 7.1599x; 7.1599x over previous
//
#include <hip/hip_runtime.h>
#include <hip/hip_bf16.h>
#include <math.h>

#define B_ 64
#define S_ 512
#define I_ 256
#define H_ 1024
#define O_ 256

#define OUT_OFF (B_*O_)      // 16384 floats: final output
#define SLOT    (B_*H_)      // 65536 floats per hidden timestep slot

typedef __attribute__((ext_vector_type(8))) short bf16x8;  // 8 bf16 = 4 VGPRs
typedef __attribute__((ext_vector_type(4))) float f32x4;

#define LDSK 1032            // padded row stride (1024 + 8 bf16): banks (4n+4q)%32 -> 2-way (free)

// ---------------- zero hidden slot 0 (h0 = 0) + hbf0 ----------------
__global__ void k_zero(float* __restrict__ hid, float* __restrict__ hbf0) {
    int i = blockIdx.x * 256 + threadIdx.x;          // 64 blocks * 256 = 16384 float4
    ((float4*)hid)[i] = make_float4(0.f, 0.f, 0.f, 0.f);
    if (i < B_ * H_ * 2 / 16)                        // 8192 float4 = 128 KB bf16 zeros
        ((float4*)hbf0)[i] = make_float4(0.f, 0.f, 0.f, 0.f);
}

// ---------------- convert whh fp32 -> bf16 (natural row-major layout) ----------------
__global__ void k_cvt(const float* __restrict__ src, unsigned short* __restrict__ dst) {
    int i = blockIdx.x * 256 + threadIdx.x;          // 1024 blocks: 4 elems each
    float4 v = ((const float4*)src)[i];
    ushort4 o;
    o.x = __builtin_bit_cast(unsigned short, __float2bfloat16(v.x));
    o.y = __builtin_bit_cast(unsigned short, __float2bfloat16(v.y));
    o.z = __builtin_bit_cast(unsigned short, __float2bfloat16(v.z));
    o.w = __builtin_bit_cast(unsigned short, __float2bfloat16(v.w));
    ((ushort4*)dst)[i] = o;
}

// ---------------- generic transpose src[R][C] -> dst[C][R] ----------------
__global__ void k_transpose(const float* __restrict__ src, float* __restrict__ dst,
                            int R, int C) {
    __shared__ float tile[32][33];
    int c0 = blockIdx.x * 32, r0 = blockIdx.y * 32;
    int tx = threadIdx.x, ty = threadIdx.y;          // block (32,8)
#pragma unroll
    for (int j = 0; j < 32; j += 8)
        tile[ty + j][tx] = src[(size_t)(r0 + ty + j) * C + c0 + tx];
    __syncthreads();
#pragma unroll
    for (int j = 0; j < 32; j += 8)
        dst[(size_t)(c0 + ty + j) * R + r0 + tx] = tile[tx][ty + j];
}

// ---------------- x_proj: hid[t+1][b][h] = bias[h] + sum_i x[b][t][i] * W_ih[h][i] ----------------
__global__ __launch_bounds__(256) void k_xproj(const float* __restrict__ x,
                                               const float* __restrict__ wihT, // [I_][H_]
                                               const float* __restrict__ bias,
                                               float* __restrict__ hid) {
    const int t   = blockIdx.x;
    const int hq0 = blockIdx.y * 16;                 // h-quad base (64 h per tile)
    __shared__ float xs[B_][260];                    // +4 pad
    const int tid = threadIdx.x;

#pragma unroll
    for (int it = 0; it < 16; ++it) {
        int f4 = it * 256 + tid;
        int b = f4 >> 6, iq = f4 & 63;
        float4 v = ((const float4*)x)[(size_t)b * (S_ * I_ / 4) + t * (I_ / 4) + iq];
        *(float4*)&xs[b][iq * 4] = v;
    }
    __syncthreads();

    const int hq = tid & 15;
    const int b0 = (tid >> 4) * 4;
    float4 acc[4];
    float4 bs = ((const float4*)bias)[hq0 + hq];
#pragma unroll
    for (int i = 0; i < 4; ++i) acc[i] = bs;

    const float4* w4p = (const float4*)wihT;
#pragma unroll 4
    for (int k = 0; k < I_; ++k) {
        float4 w = w4p[(size_t)k * (H_ / 4) + hq0 + hq];
#pragma unroll
        for (int i = 0; i < 4; ++i) {
            float xv = xs[b0 + i][k];
            acc[i].x += xv * w.x; acc[i].y += xv * w.y;
            acc[i].z += xv * w.z; acc[i].w += xv * w.w;
        }
    }

    float4* out4 = (float4*)hid;
#pragma unroll
    for (int i = 0; i < 4; ++i)
        out4[(size_t)(t + 1) * (SLOT / 4) + (b0 + i) * (H_ / 4) + hq0 + hq] = acc[i];
}

// ---------------- one recurrence step (bf16 MFMA) ----------------
// D[16r x 16b] = W_rows[16 x 1024] * hT[1024 x 16b]; A = whhbf rows (LDS), B = hprev (global).
// grid 64 (slice = 16 r-rows), 256 thr = 4 waves, wave w = b-tile.
__global__ __launch_bounds__(256) void k_step(
    const unsigned short* __restrict__ whhbf,   // [H_][H_] bf16 natural
    const unsigned short* __restrict__ hprev,   // [B_][H_] bf16
    unsigned short* __restrict__ hnext,         // [B_][H_] bf16
    float* __restrict__ hid, int t)
{
    const int slice = blockIdx.x;
    __shared__ unsigned short Ws[16 * LDSK];
    const int tid = threadIdx.x;

    // stage 16 W rows (contiguous 32 KB) -> padded LDS
    {
        const float4* src = (const float4*)(whhbf + (size_t)slice * 16 * H_);
#pragma unroll
        for (int it = 0; it < 8; ++it) {
            int c = it * 256 + tid;                  // 2048 chunks of 16B (8 bf16)
            float4 v = src[c];
            int row = c >> 7, off = (c & 127) * 8;
            *(float4*)&Ws[row * LDSK + off] = v;
        }
    }
    __syncthreads();

    const int w    = tid >> 6;                       // wave = b-tile
    const int lane = tid & 63;
    const int n    = lane & 15;                      // A-row (r_local) AND B-col (b_local)
    const int quad = lane >> 4;

    const int b = w * 16 + n;
    f32x4 acc = {0.f, 0.f, 0.f, 0.f};

    const unsigned short* ap = &Ws[n * LDSK + quad * 8];
    const unsigned short* bp = hprev + (size_t)b * H_ + quad * 8;

#pragma unroll
    for (int kk = 0; kk < 32; ++kk) {
        bf16x8 af = *(const bf16x8*)(ap + kk * 32);
        bf16x8 bf = *(const bf16x8*)(bp + kk * 32);
        acc = __builtin_amdgcn_mfma_f32_16x16x32_bf16(af, bf, acc, 0, 0, 0);
    }

    // C/D: row(M=r_local) = quad*4 + reg, col(N=b_local) = lane&15
    const int r0 = slice * 16 + quad * 4;
    float4* slot1 = (float4*)(hid + (size_t)(t + 1) * SLOT);
    size_t idx = (size_t)b * (H_ / 4) + (r0 >> 2);
    float4 xp = slot1[idx];                          // x_proj + bias (precomputed)
    float4 hv;
    hv.x = tanhf(acc[0] + xp.x);
    hv.y = tanhf(acc[1] + xp.y);
    hv.z = tanhf(acc[2] + xp.z);
    hv.w = tanhf(acc[3] + xp.w);
    slot1[idx] = hv;

    ushort4 hb;
    hb.x = __builtin_bit_cast(unsigned short, __float2bfloat16(hv.x));
    hb.y = __builtin_bit_cast(unsigned short, __float2bfloat16(hv.y));
    hb.z = __builtin_bit_cast(unsigned short, __float2bfloat16(hv.z));
    hb.w = __builtin_bit_cast(unsigned short, __float2bfloat16(hv.w));
    *(ushort4*)(hnext + (size_t)b * H_ + r0) = hb;
}

// ---------------- final fc ----------------
__global__ __launch_bounds__(256) void k_fc(const float* __restrict__ fcwT,  // [H_][O_]
                                            const float* __restrict__ fcb,
                                            const float* __restrict__ hid,
                                            float* __restrict__ outp) {
    const int b = blockIdx.x;
    __shared__ float hl[H_];
    const int tid = threadIdx.x;
    ((float4*)hl)[tid] = ((const float4*)(hid + (size_t)S_ * SLOT + b * H_))[tid];
    __syncthreads();
    float acc = fcb[tid];
#pragma unroll 4
    for (int k = 0; k < H_; ++k)
        acc += fcwT[(size_t)k * O_ + tid] * hl[k];
    outp[b * O_ + tid] = acc;
}

extern "C" void kernel_launch(void* const* d_in, const int* in_sizes, int n_in,
                              void* d_out, int out_size, void* d_ws, size_t ws_size,
                              hipStream_t stream) {
    const float* x    = (const float*)d_in[0];
    const float* wih  = (const float*)d_in[1];
    const float* whh  = (const float*)d_in[2];
    const float* bias = (const float*)d_in[3];
    const float* fcw  = (const float*)d_in[4];
    const float* fcb  = (const float*)d_in[5];

    float* outp = (float*)d_out;
    float* hid  = outp + OUT_OFF;

    // ws layout: whhbf 2MB | hbf0 128KB | hbf1 128KB | wihT 1MB | fcwT 1MB  (≈4.3MB)
    unsigned short* whhbf = (unsigned short*)d_ws;
    unsigned short* hbf0  = whhbf + (size_t)H_ * H_;
    unsigned short* hbf1  = hbf0 + (size_t)B_ * H_;
    float* wihT = (float*)(hbf1 + (size_t)B_ * H_);
    float* fcwT = wihT + (size_t)I_ * H_;

    k_zero<<<SLOT / 4 / 256, 256, 0, stream>>>(hid, (float*)hbf0);
    k_cvt<<<H_ * H_ / 4 / 256, 256, 0, stream>>>(whh, whhbf);
    k_transpose<<<dim3(I_ / 32, H_ / 32), dim3(32, 8), 0, stream>>>(wih, wihT, H_, I_);
    k_transpose<<<dim3(H_ / 32, O_ / 32), dim3(32, 8), 0, stream>>>(fcw, fcwT, O_, H_);

    k_xproj<<<dim3(S_, H_ / 64), 256, 0, stream>>>(x, wihT, bias, hid);

    unsigned short* hp[2] = {hbf0, hbf1};
    for (int t = 0; t < S_; ++t)
        k_step<<<64, 256, 0, stream>>>(whhbf, hp[t & 1], hp[(t + 1) & 1], hid, t);

    k_fc<<<B_, 256, 0, stream>>>(fcwT, fcb, hid, outp);
}